// Round 4
// baseline (110.148 us; speedup 1.0000x reference)
//
#include <hip/hip_runtime.h>
#include <hip/hip_bf16.h>
#include <string.h>

// out[n,f] = weights[n] * ( x[n,:] . Wsum[f,:] + bsum[f] )
// Wsum = sum_e W[e] (bf16), bsum = sum_e b[e]  (expert sum commutes with Linear)

#define N_TOK 32768
#define DIM   512
#define NEXP  8

typedef __attribute__((ext_vector_type(8))) short  bf16x8;
typedef __attribute__((ext_vector_type(4))) float  f32x4;

__device__ __forceinline__ unsigned int pk2bf(float a, float b) {
    unsigned ua = __float_as_uint(a), ub = __float_as_uint(b);
    ua = (ua + 0x7FFFu + ((ua >> 16) & 1u)) >> 16;   // RNE to bf16
    ub = (ub + 0x7FFFu + ((ub >> 16) & 1u)) >> 16;
    return ua | (ub << 16);
}

// ---------------- prep: Wsum (bf16, linear [DIM][DIM]) + bsum (f32) ----------------
__global__ __launch_bounds__(256) void moe_prep(const float* __restrict__ W,
                                                const float* __restrict__ b,
                                                unsigned short* __restrict__ Wsum,
                                                float* __restrict__ bsum) {
    int g  = blockIdx.x * 256 + threadIdx.x;     // 0 .. 65535
    int e4 = g * 4;
    float4 s = make_float4(0.f, 0.f, 0.f, 0.f);
#pragma unroll
    for (int e = 0; e < NEXP; ++e) {
        float4 v = *(const float4*)(W + e * (DIM * DIM) + e4);
        s.x += v.x; s.y += v.y; s.z += v.z; s.w += v.w;
    }
    uint2 o;
    o.x = pk2bf(s.x, s.y);
    o.y = pk2bf(s.z, s.w);
    *(uint2*)(Wsum + e4) = o;

    if (g < DIM / 4) {
        float4 bs = make_float4(0.f, 0.f, 0.f, 0.f);
#pragma unroll
        for (int e = 0; e < NEXP; ++e) {
            float4 v = *(const float4*)(b + e * DIM + g * 4);
            bs.x += v.x; bs.y += v.y; bs.z += v.z; bs.w += v.w;
        }
        *(float4*)(bsum + g * 4) = bs;
    }
}

// ---------------- main GEMM: barrier-free, LDS-free, wave-independent ----------------
// Each wave: 64-token x 64-feature output tile, K=512 in 16 slices of 32.
// A fragments read per-lane from x (f32 -> bf16 in regs); B fragments per-lane from
// Wsum (512 KB, L2-resident). Software pipeline depth 1 with named even/odd regs.
// MFMA operands swapped (mfma(B,A)): lane owns 4 consecutive features of one token
// -> direct dwordx4 stores (layout proven in R2).
__global__ __launch_bounds__(256, 3) void moe_gemm(const float* __restrict__ x,
                                                   const float* __restrict__ wts,
                                                   const unsigned short* __restrict__ Ws,
                                                   const float* __restrict__ bsum,
                                                   float* __restrict__ out) {
    const int tid  = threadIdx.x;
    const int lane = tid & 63;
    const int w    = tid >> 6;       // wave 0..3
    const int lr   = lane & 15;
    const int lg   = lane >> 4;

    // XCD-chunked swizzle: 1024 blocks, hw XCD = blockIdx % 8. Give each XCD a
    // contiguous 128-block chunk of the original order so the two feature-halves
    // of a token tile + 63 neighboring token tiles share one L2 (x reuse x8).
    const int L    = blockIdx.x;
    const int orig = (L & 7) * 128 + (L >> 3);
    const int m0   = (orig >> 1) * 64;            // token tile base
    const int f0   = (orig & 1) * 256 + w * 64;   // feature slice base

    const float*          abase = x  + (size_t)(m0 + lr) * DIM + lg * 8;
    const unsigned short* bbase = Ws + (size_t)(f0 + lr) * DIM + lg * 8;

    f32x4 acc[4][4] = {};   // acc[j][i]: j = feature frag, i = token frag
    bf16x8 aE[4], aO[4], bE[4], bO[4];

    auto loadB = [&](int ks, bf16x8 (&bb)[4]) {
#pragma unroll
        for (int j = 0; j < 4; ++j)
            bb[j] = *(const bf16x8*)(bbase + j * 16 * DIM + ks * 32);
    };
    auto loadA = [&](int ks, bf16x8 (&aa)[4]) {
#pragma unroll
        for (int i = 0; i < 4; ++i) {
            const float4* p = (const float4*)(abase + (size_t)i * 16 * DIM + ks * 32);
            float4 u0 = p[0], u1 = p[1];
            uint4 v;
            v.x = pk2bf(u0.x, u0.y); v.y = pk2bf(u0.z, u0.w);
            v.z = pk2bf(u1.x, u1.y); v.w = pk2bf(u1.z, u1.w);
            __builtin_memcpy(&aa[i], &v, 16);
        }
    };
    auto comp = [&](bf16x8 (&aa)[4], bf16x8 (&bb)[4]) {
#pragma unroll
        for (int j = 0; j < 4; ++j)
#pragma unroll
            for (int i = 0; i < 4; ++i)
                acc[j][i] = __builtin_amdgcn_mfma_f32_16x16x32_bf16(bb[j], aa[i], acc[j][i], 0, 0, 0);
    };

    loadA(0, aE); loadB(0, bE);
#pragma unroll
    for (int it = 0; it < 8; ++it) {
        loadA(2 * it + 1, aO); loadB(2 * it + 1, bO);   // prefetch odd slice
        comp(aE, bE);
        if (it < 7) { loadA(2 * it + 2, aE); loadB(2 * it + 2, bE); }  // prefetch even
        comp(aO, bO);
    }

    // ---- epilogue: direct stores. Lane (lr,lg), frag (j,i):
    //      token = m0 + i*16 + lr;  features = f0 + j*16 + lg*4 + [0..3]
    f32x4 bs4[4];
#pragma unroll
    for (int j = 0; j < 4; ++j)
        bs4[j] = *(const f32x4*)(bsum + f0 + j * 16 + lg * 4);

#pragma unroll
    for (int i = 0; i < 4; ++i) {
        const int row = m0 + i * 16 + lr;
        const float wt = wts[row];
#pragma unroll
        for (int j = 0; j < 4; ++j) {
            f32x4 v;
            v[0] = wt * (acc[j][i][0] + bs4[j][0]);
            v[1] = wt * (acc[j][i][1] + bs4[j][1]);
            v[2] = wt * (acc[j][i][2] + bs4[j][2]);
            v[3] = wt * (acc[j][i][3] + bs4[j][3]);
            *(f32x4*)(out + (size_t)row * DIM + f0 + j * 16 + lg * 4) = v;
        }
    }
}

extern "C" void kernel_launch(void* const* d_in, const int* in_sizes, int n_in,
                              void* d_out, int out_size, void* d_ws, size_t ws_size,
                              hipStream_t stream) {
    const float* x   = (const float*)d_in[0];   // [N, D]
    const float* wts = (const float*)d_in[1];   // [N, 1]
    const float* W   = (const float*)d_in[2];   // [E, D, D]
    const float* b   = (const float*)d_in[3];   // [E, D]
    float* out       = (float*)d_out;           // [N, D]

    unsigned short* Wsum = (unsigned short*)d_ws;                    // 512 KB bf16
    float*          bsum = (float*)((char*)d_ws + DIM * DIM * 2);    // 2 KB f32

    moe_prep<<<dim3((DIM * DIM / 4) / 256), dim3(256), 0, stream>>>(W, b, Wsum, bsum);

    moe_gemm<<<dim3((N_TOK / 64) * (DIM / 256)), dim3(256), 0, stream>>>(x, wts, Wsum, bsum, out);
}

// Round 5
// 59.108 us; speedup vs baseline: 1.8635x; 1.8635x over previous
//
#include <hip/hip_runtime.h>
#include <hip/hip_bf16.h>

// out[n,f] = weights[n] * ( x[n,:] . Wsum[f,:] + bsum[f] )
// Wsum = sum_e W[e] (bf16), bsum = sum_e b[e]  (expert sum commutes with Linear)

#define N_TOK 32768
#define DIM   512
#define NEXP  8
#define BM    64            // tokens per block

typedef __attribute__((ext_vector_type(8))) short  bf16x8;
typedef __attribute__((ext_vector_type(4))) float  f32x4;

__device__ __forceinline__ unsigned int pk2bf(float a, float b) {
    unsigned ua = __float_as_uint(a), ub = __float_as_uint(b);
    ua = (ua + 0x7FFFu + ((ua >> 16) & 1u)) >> 16;   // RNE to bf16
    ub = (ub + 0x7FFFu + ((ub >> 16) & 1u)) >> 16;
    return ua | (ub << 16);
}

// ---------------- prep: Wsum (bf16, linear [DIM][DIM]) + bsum (f32) ----------------
__global__ __launch_bounds__(256) void moe_prep(const float* __restrict__ W,
                                                const float* __restrict__ b,
                                                unsigned short* __restrict__ Wsum,
                                                float* __restrict__ bsum) {
    int g  = blockIdx.x * 256 + threadIdx.x;     // 0 .. 65535
    int e4 = g * 4;
    float4 s = make_float4(0.f, 0.f, 0.f, 0.f);
#pragma unroll
    for (int e = 0; e < NEXP; ++e) {
        float4 v = *(const float4*)(W + e * (DIM * DIM) + e4);
        s.x += v.x; s.y += v.y; s.z += v.z; s.w += v.w;
    }
    uint2 o;
    o.x = pk2bf(s.x, s.y);
    o.y = pk2bf(s.z, s.w);
    *(uint2*)(Wsum + e4) = o;

    if (g < DIM / 4) {
        float4 bs = make_float4(0.f, 0.f, 0.f, 0.f);
#pragma unroll
        for (int e = 0; e < NEXP; ++e) {
            float4 v = *(const float4*)(b + e * DIM + g * 4);
            bs.x += v.x; bs.y += v.y; bs.z += v.z; bs.w += v.w;
        }
        *(float4*)(bsum + g * 4) = bs;
    }
}

// ---------------- main GEMM: stage-A-once, then barrier-free K-loop ----------------
// Block = 64 tokens x all 512 features; 8 waves, wave w owns features [w*64,(w+1)*64).
// A (x, f32->bf16) staged ONCE into 64KB LDS (XOR-swizzled, R2-proven pattern),
// single __syncthreads, then 16 x (4 B-loads from L2-resident Wsum + 4 ds_read_b128
// + 16 MFMA) with NO barriers -- waves run free, compiler pipelines loads.
// MFMA operands swapped (mfma(B,A)): lane owns 4 consecutive features of one token
// -> direct dwordx4 stores (1.02x write amplification, proven in R3).
__global__ __launch_bounds__(512, 4) void moe_gemm(const float* __restrict__ x,
                                                   const float* __restrict__ wts,
                                                   const unsigned short* __restrict__ Ws,
                                                   const float* __restrict__ bsum,
                                                   float* __restrict__ out) {
    __shared__ __align__(16) unsigned char ldsA[BM * DIM * 2];   // 64 KB

    const int tid  = threadIdx.x;
    const int lane = tid & 63;
    const int w    = tid >> 6;       // wave 0..7
    const int lr   = lane & 15;
    const int lg   = lane >> 4;
    const int m0   = blockIdx.x * BM;
    const int f0   = w * 64;

    // ---- stage A once: thread -> row tid>>3, 8 f32 per iter (wave: 8 rows x 256B chunks)
    {
        const int row = tid >> 3;
        const int s0  = tid & 7;
        const float* src = x + (size_t)(m0 + row) * DIM + s0 * 8;
        unsigned char* dst = ldsA + row * 1024 + ((s0 ^ (row & 7)) << 4);
#pragma unroll
        for (int i = 0; i < 8; ++i) {              // slots i*8 + s0, swizzled low-3-bits
            float4 u0 = *(const float4*)(src + i * 64);
            float4 u1 = *(const float4*)(src + i * 64 + 4);
            uint4 v;
            v.x = pk2bf(u0.x, u0.y); v.y = pk2bf(u0.z, u0.w);
            v.z = pk2bf(u1.x, u1.y); v.w = pk2bf(u1.z, u1.w);
            *(uint4*)(dst + i * 128) = v;
        }
    }
    __syncthreads();   // the ONLY barrier

    // ---- B fragment base (R2/R3-proven): lane (lr,lg) reads feature row f0+j*16+lr,
    //      k = ks*32 + lg*8
    const unsigned short* bbase = Ws + (size_t)(f0 + lr) * DIM + lg * 8;

    f32x4 acc[4][4] = {};   // acc[j][i]: j = feature frag, i = token frag

#pragma unroll
    for (int ks = 0; ks < DIM / 32; ++ks) {        // 16 slices of k=32
        bf16x8 bf[4], af[4];
#pragma unroll
        for (int j = 0; j < 4; ++j)
            bf[j] = *(const bf16x8*)(bbase + j * 16 * DIM + ks * 32);
#pragma unroll
        for (int i = 0; i < 4; ++i) {
            const int row = i * 16 + lr;
            const int sl  = ks * 4 + lg;
            const int sw  = (sl & ~7) | ((sl ^ row) & 7);
            af[i] = *(const bf16x8*)(ldsA + row * 1024 + sw * 16);
        }
#pragma unroll
        for (int j = 0; j < 4; ++j)
#pragma unroll
            for (int i = 0; i < 4; ++i)
                acc[j][i] = __builtin_amdgcn_mfma_f32_16x16x32_bf16(bf[j], af[i], acc[j][i], 0, 0, 0);
    }

    // ---- epilogue: direct stores (R3 pattern, 1.02x write amp).
    //      token = m0 + i*16 + lr;  features = f0 + j*16 + lg*4 + [0..3]
    f32x4 bs4[4];
#pragma unroll
    for (int j = 0; j < 4; ++j)
        bs4[j] = *(const f32x4*)(bsum + f0 + j * 16 + lg * 4);

#pragma unroll
    for (int i = 0; i < 4; ++i) {
        const int row = m0 + i * 16 + lr;
        const float wt = wts[row];
#pragma unroll
        for (int j = 0; j < 4; ++j) {
            f32x4 v;
            v[0] = wt * (acc[j][i][0] + bs4[j][0]);
            v[1] = wt * (acc[j][i][1] + bs4[j][1]);
            v[2] = wt * (acc[j][i][2] + bs4[j][2]);
            v[3] = wt * (acc[j][i][3] + bs4[j][3]);
            *(f32x4*)(out + (size_t)row * DIM + f0 + j * 16 + lg * 4) = v;
        }
    }
}

extern "C" void kernel_launch(void* const* d_in, const int* in_sizes, int n_in,
                              void* d_out, int out_size, void* d_ws, size_t ws_size,
                              hipStream_t stream) {
    const float* x   = (const float*)d_in[0];   // [N, D]
    const float* wts = (const float*)d_in[1];   // [N, 1]
    const float* W   = (const float*)d_in[2];   // [E, D, D]
    const float* b   = (const float*)d_in[3];   // [E, D]
    float* out       = (float*)d_out;           // [N, D]

    unsigned short* Wsum = (unsigned short*)d_ws;                    // 512 KB bf16
    float*          bsum = (float*)((char*)d_ws + DIM * DIM * 2);    // 2 KB f32

    moe_prep<<<dim3((DIM * DIM / 4) / 256), dim3(256), 0, stream>>>(W, b, Wsum, bsum);

    moe_gemm<<<dim3(N_TOK / BM), dim3(512), 0, stream>>>(x, wts, Wsum, bsum, out);
}

// Round 6
// 56.724 us; speedup vs baseline: 1.9418x; 1.0420x over previous
//
#include <hip/hip_runtime.h>
#include <hip/hip_bf16.h>

// out[n,f] = weights[n] * ( x[n,:] . Wsum[f,:] + bsum[f] )
// Wsum = sum_e W[e] (bf16), bsum = sum_e b[e]  (expert sum commutes with Linear)

#define N_TOK 32768
#define DIM   512
#define NEXP  8
#define BM    64            // tokens per block

typedef __attribute__((ext_vector_type(8))) short  bf16x8;
typedef __attribute__((ext_vector_type(4))) float  f32x4;

__device__ __forceinline__ unsigned int pk2bf(float a, float b) {
    unsigned ua = __float_as_uint(a), ub = __float_as_uint(b);
    ua = (ua + 0x7FFFu + ((ua >> 16) & 1u)) >> 16;   // RNE to bf16
    ub = (ub + 0x7FFFu + ((ub >> 16) & 1u)) >> 16;
    return ua | (ub << 16);
}

// ---------------- prep: Wsum (bf16, linear [DIM][DIM]) + bsum (f32) ----------------
__global__ __launch_bounds__(256) void moe_prep(const float* __restrict__ W,
                                                const float* __restrict__ b,
                                                unsigned short* __restrict__ Wsum,
                                                float* __restrict__ bsum) {
    int g  = blockIdx.x * 256 + threadIdx.x;     // 0 .. 65535
    int e4 = g * 4;
    float4 s = make_float4(0.f, 0.f, 0.f, 0.f);
#pragma unroll
    for (int e = 0; e < NEXP; ++e) {
        float4 v = *(const float4*)(W + e * (DIM * DIM) + e4);
        s.x += v.x; s.y += v.y; s.z += v.z; s.w += v.w;
    }
    uint2 o;
    o.x = pk2bf(s.x, s.y);
    o.y = pk2bf(s.z, s.w);
    *(uint2*)(Wsum + e4) = o;

    if (g < DIM / 4) {
        float4 bs = make_float4(0.f, 0.f, 0.f, 0.f);
#pragma unroll
        for (int e = 0; e < NEXP; ++e) {
            float4 v = *(const float4*)(b + e * DIM + g * 4);
            bs.x += v.x; bs.y += v.y; bs.z += v.z; bs.w += v.w;
        }
        *(float4*)(bsum + g * 4) = bs;
    }
}

// ---------------- main GEMM ----------------
// Block = 64 tokens x all 512 features; 8 waves, wave w owns features [w*64,(w+1)*64).
// A (x, f32->bf16) staged into 64KB LDS in 4 QUARTERS interleaved with the K-loop:
// quarter q+1's global loads issue at the start of compute chunk q (4 slices of
// MFMA cover the HBM latency), convert+ds_write at chunk end, barrier. Reads are
// spread over the whole block lifetime instead of one burst (duty-cycle fix).
// B (Wsum, L2-resident) per-lane with 2-deep named-reg prefetch (bE/bO).
// MFMA operands swapped (mfma(B,A)): lane owns 4 consecutive features of one token
// -> direct dwordx4 stores (1.02-1.19x write amp, proven R3/R4).
__global__ __launch_bounds__(512, 2) void moe_gemm(const float* __restrict__ x,
                                                   const float* __restrict__ wts,
                                                   const unsigned short* __restrict__ Ws,
                                                   const float* __restrict__ bsum,
                                                   float* __restrict__ out) {
    __shared__ __align__(16) unsigned char ldsA[BM * DIM * 2];   // 64 KB

    const int tid  = threadIdx.x;
    const int lane = tid & 63;
    const int w    = tid >> 6;       // wave 0..7
    const int lr   = lane & 15;
    const int lg   = lane >> 4;
    const int m0   = blockIdx.x * BM;
    const int f0   = w * 64;

    // A staging geometry: thread -> row tid>>3 (0..63), k-slot s0 = tid&7.
    // Quarter q: granules g = q*16 + s0 + u*8 (u=0,1), each granule = 8 f32 -> 16B bf16.
    const int arow = tid >> 3;
    const int as0  = tid & 7;
    const float* asrc = x + (size_t)(m0 + arow) * DIM;
    unsigned char* arowp = ldsA + arow * 1024;

    float4 fA[4], fB[4];           // two named staging reg sets (quarters alternate)

    auto loadQ = [&](int q, float4 (&r)[4]) {
#pragma unroll
        for (int u = 0; u < 2; ++u) {
            const float* p = asrc + (q * 16 + as0 + u * 8) * 8;
            r[2 * u]     = *(const float4*)p;
            r[2 * u + 1] = *(const float4*)(p + 4);
        }
    };
    auto writeQ = [&](int q, float4 (&r)[4]) {
#pragma unroll
        for (int u = 0; u < 2; ++u) {
            const int g  = q * 16 + as0 + u * 8;
            const int sg = (g & ~7) | ((g ^ arow) & 7);   // XOR swizzle (R4-proven)
            uint4 v;
            v.x = pk2bf(r[2 * u].x,     r[2 * u].y);
            v.y = pk2bf(r[2 * u].z,     r[2 * u].w);
            v.z = pk2bf(r[2 * u + 1].x, r[2 * u + 1].y);
            v.w = pk2bf(r[2 * u + 1].z, r[2 * u + 1].w);
            *(uint4*)(arowp + sg * 16) = v;
        }
    };

    // B fragments: lane (lr,lg) reads feature row f0 + j*16 + lr, k = s*32 + lg*8
    const unsigned short* bbase = Ws + (size_t)(f0 + lr) * DIM + lg * 8;
    bf16x8 bE[4], bO[4], af[4];

    auto loadB = [&](int s, bf16x8 (&bb)[4]) {
#pragma unroll
        for (int j = 0; j < 4; ++j)
            bb[j] = *(const bf16x8*)(bbase + j * 16 * DIM + s * 32);
    };
    auto sliceA = [&](int s) {
#pragma unroll
        for (int i = 0; i < 4; ++i) {
            const int row = i * 16 + lr;
            const int gsl = s * 4 + lg;
            const int sw  = (gsl & ~7) | ((gsl ^ row) & 7);
            af[i] = *(const bf16x8*)(ldsA + row * 1024 + sw * 16);
        }
    };

    f32x4 acc[4][4] = {};   // acc[j][i]: j = feature frag, i = token frag
    auto mf = [&](bf16x8 (&bb)[4]) {
#pragma unroll
        for (int j = 0; j < 4; ++j)
#pragma unroll
            for (int i = 0; i < 4; ++i)
                acc[j][i] = __builtin_amdgcn_mfma_f32_16x16x32_bf16(bb[j], af[i], acc[j][i], 0, 0, 0);
    };

#define SLICE_E(s) { if ((s) + 1 < 16) loadB((s) + 1, bO); sliceA(s); mf(bE); }
#define SLICE_O(s) { if ((s) + 1 < 16) loadB((s) + 1, bE); sliceA(s); mf(bO); }

    // ---- prologue: quarter 0 staged; quarter 1 loads in flight
    loadQ(0, fA);
    loadQ(1, fB);
    writeQ(0, fA);          // counted vmcnt: waits only fA's 4 loads
    loadB(0, bE);
    __syncthreads();

    // ---- chunk 0: slices 0-3 | loadQ2 early, writeQ1 late
    loadQ(2, fA);
    SLICE_E(0) SLICE_O(1) SLICE_E(2) SLICE_O(3)
    writeQ(1, fB);
    __syncthreads();

    // ---- chunk 1: slices 4-7 | loadQ3 early, writeQ2 late
    loadQ(3, fB);
    SLICE_E(4) SLICE_O(5) SLICE_E(6) SLICE_O(7)
    writeQ(2, fA);
    __syncthreads();

    // ---- chunk 2: slices 8-11 | writeQ3 late
    SLICE_E(8) SLICE_O(9) SLICE_E(10) SLICE_O(11)
    writeQ(3, fB);
    __syncthreads();

    // ---- chunk 3: slices 12-15
    SLICE_E(12) SLICE_O(13) SLICE_E(14) SLICE_O(15)

#undef SLICE_E
#undef SLICE_O

    // ---- epilogue: direct stores. token = m0 + i*16 + lr; feats = f0 + j*16 + lg*4
    f32x4 bs4[4];
#pragma unroll
    for (int j = 0; j < 4; ++j)
        bs4[j] = *(const f32x4*)(bsum + f0 + j * 16 + lg * 4);

#pragma unroll
    for (int i = 0; i < 4; ++i) {
        const int row = m0 + i * 16 + lr;
        const float wt = wts[row];
#pragma unroll
        for (int j = 0; j < 4; ++j) {
            f32x4 v;
            v[0] = wt * (acc[j][i][0] + bs4[j][0]);
            v[1] = wt * (acc[j][i][1] + bs4[j][1]);
            v[2] = wt * (acc[j][i][2] + bs4[j][2]);
            v[3] = wt * (acc[j][i][3] + bs4[j][3]);
            *(f32x4*)(out + (size_t)row * DIM + f0 + j * 16 + lg * 4) = v;
        }
    }
}

extern "C" void kernel_launch(void* const* d_in, const int* in_sizes, int n_in,
                              void* d_out, int out_size, void* d_ws, size_t ws_size,
                              hipStream_t stream) {
    const float* x   = (const float*)d_in[0];   // [N, D]
    const float* wts = (const float*)d_in[1];   // [N, 1]
    const float* W   = (const float*)d_in[2];   // [E, D, D]
    const float* b   = (const float*)d_in[3];   // [E, D]
    float* out       = (float*)d_out;           // [N, D]

    unsigned short* Wsum = (unsigned short*)d_ws;                    // 512 KB bf16
    float*          bsum = (float*)((char*)d_ws + DIM * DIM * 2);    // 2 KB f32

    moe_prep<<<dim3((DIM * DIM / 4) / 256), dim3(256), 0, stream>>>(W, b, Wsum, bsum);

    moe_gemm<<<dim3(N_TOK / BM), dim3(512), 0, stream>>>(x, wts, Wsum, bsum, out);
}

// Round 7
// 44.159 us; speedup vs baseline: 2.4943x; 1.2845x over previous
//
#include <hip/hip_runtime.h>
#include <hip/hip_bf16.h>

// out[n,f] = weights[n] * ( x[n,:] . Wsum[f,:] + bsum[f] )
// Wsum = sum_e W[e], bsum = sum_e b[e]  (expert sum commutes with Linear).
// Wsum is stored in MFMA-FRAGMENT-MAJOR order ("Bfrag") so the GEMM's B-loads are
// lane-consecutive dense streams (no 16-line gathers -- R2-R5's hidden serializer).

#define N_TOK 32768
#define DIM   512
#define NEXP  8
#define BM    64            // tokens per block

typedef __attribute__((ext_vector_type(8))) short  bf16x8;
typedef __attribute__((ext_vector_type(4))) float  f32x4;

__device__ __forceinline__ unsigned int pk2bf(float a, float b) {
    unsigned ua = __float_as_uint(a), ub = __float_as_uint(b);
    ua = (ua + 0x7FFFu + ((ua >> 16) & 1u)) >> 16;   // RNE to bf16
    ub = (ub + 0x7FFFu + ((ub >> 16) & 1u)) >> 16;
    return ua | (ub << 16);
}

// ---------------- prep: Bfrag (bf16, fragment-major) + bsum (f32) ----------------
// Thread g (0..32767): feature f = g>>6, k-granule q = g&63 (8 k each).
// Fragment coords: F = f>>6 (wave slice), j = (f>>4)&3, lr = f&15; s = q>>2, lg = q&3.
// Bfrag 16B-index = ((F*4 + j)*16 + s)*64 + (lg*16 + lr)  -> lane-consecutive loads.
__global__ __launch_bounds__(256) void moe_prep(const float* __restrict__ W,
                                                const float* __restrict__ b,
                                                unsigned short* __restrict__ Bfrag,
                                                float* __restrict__ bsum) {
    const int g = blockIdx.x * 256 + threadIdx.x;    // 0..32767
    const int f = g >> 6;
    const int q = g & 63;
    const float* src = W + (size_t)f * DIM + q * 8;
    float s0 = 0, s1 = 0, s2 = 0, s3 = 0, s4 = 0, s5 = 0, s6 = 0, s7 = 0;
#pragma unroll
    for (int e = 0; e < NEXP; ++e) {
        float4 u0 = *(const float4*)(src + (size_t)e * DIM * DIM);
        float4 u1 = *(const float4*)(src + (size_t)e * DIM * DIM + 4);
        s0 += u0.x; s1 += u0.y; s2 += u0.z; s3 += u0.w;
        s4 += u1.x; s5 += u1.y; s6 += u1.z; s7 += u1.w;
    }
    uint4 v;
    v.x = pk2bf(s0, s1); v.y = pk2bf(s2, s3);
    v.z = pk2bf(s4, s5); v.w = pk2bf(s6, s7);

    const int F  = f >> 6, j = (f >> 4) & 3, lr = f & 15;
    const int sl = q >> 2, lg = q & 3;
    const int idx16 = ((F * 4 + j) * 16 + sl) * 64 + (lg * 16 + lr);
    *(uint4*)(Bfrag + (size_t)idx16 * 8) = v;

    if (g < DIM / 4) {
        float4 bs = make_float4(0.f, 0.f, 0.f, 0.f);
#pragma unroll
        for (int e = 0; e < NEXP; ++e) {
            float4 u = *(const float4*)(b + e * DIM + g * 4);
            bs.x += u.x; bs.y += u.y; bs.z += u.z; bs.w += u.w;
        }
        *(float4*)(bsum + g * 4) = bs;
    }
}

// ---------------- main GEMM: stage-A-once + barrier-free K-loop + dense B ----------------
// Block = 64 tokens x all 512 features; 8 waves, wave w owns features [w*64,(w+1)*64).
// A (x, f32->bf16) staged ONCE into 64KB LDS (XOR-swizzled, R4-proven), 1 barrier.
// B loads are dense fragment-major streams from L2-resident Bfrag (512 KB).
// MFMA operands swapped (mfma(B,A)): lane owns 4 consecutive features of one token
// -> direct dwordx4 stores (1.02x write amp, proven R3/R4).
__global__ __launch_bounds__(512, 4) void moe_gemm(const float* __restrict__ x,
                                                   const float* __restrict__ wts,
                                                   const unsigned short* __restrict__ Bf,
                                                   const float* __restrict__ bsum,
                                                   float* __restrict__ out) {
    __shared__ __align__(16) unsigned char ldsA[BM * DIM * 2];   // 64 KB

    const int tid  = threadIdx.x;
    const int lane = tid & 63;
    const int w    = tid >> 6;       // wave 0..7
    const int lr   = lane & 15;
    const int lg   = lane >> 4;
    const int m0   = blockIdx.x * BM;
    const int f0   = w * 64;

    // ---- stage A once: thread -> row tid>>3, k-granule s0 = tid&7 (+ i*8), coalesced
    {
        const int row = tid >> 3;
        const int s0  = tid & 7;
        const float* src = x + (size_t)(m0 + row) * DIM + s0 * 8;
        unsigned char* dst = ldsA + row * 1024 + ((s0 ^ (row & 7)) << 4);
#pragma unroll
        for (int i = 0; i < 8; ++i) {
            float4 u0 = *(const float4*)(src + i * 64);
            float4 u1 = *(const float4*)(src + i * 64 + 4);
            uint4 v;
            v.x = pk2bf(u0.x, u0.y); v.y = pk2bf(u0.z, u0.w);
            v.z = pk2bf(u1.x, u1.y); v.w = pk2bf(u1.z, u1.w);
            *(uint4*)(dst + i * 128) = v;
        }
    }
    __syncthreads();   // the ONLY barrier

    // ---- dense B stream base: wave w's fragment block, this lane's 16B slot
    const bf16x8* bfr = (const bf16x8*)Bf + (size_t)w * 4096 + lane;   // + j*1024 + s*64

    f32x4 acc[4][4] = {};   // acc[j][i]: j = feature frag, i = token frag
    bf16x8 bE[4], bO[4], af[4];

    auto loadB = [&](int s, bf16x8 (&bb)[4]) {
#pragma unroll
        for (int j = 0; j < 4; ++j)
            bb[j] = bfr[j * 1024 + s * 64];
    };
    auto sliceA = [&](int s) {
#pragma unroll
        for (int i = 0; i < 4; ++i) {
            const int row = i * 16 + lr;
            const int gsl = s * 4 + lg;
            const int sw  = (gsl & ~7) | ((gsl ^ row) & 7);
            af[i] = *(const bf16x8*)(ldsA + row * 1024 + sw * 16);
        }
    };
    auto mf = [&](bf16x8 (&bb)[4]) {
#pragma unroll
        for (int j = 0; j < 4; ++j)
#pragma unroll
            for (int i = 0; i < 4; ++i)
                acc[j][i] = __builtin_amdgcn_mfma_f32_16x16x32_bf16(bb[j], af[i], acc[j][i], 0, 0, 0);
    };

    loadB(0, bE);
#pragma unroll
    for (int it = 0; it < 8; ++it) {
        loadB(2 * it + 1, bO);                      // prefetch odd slice
        sliceA(2 * it);
        mf(bE);
        if (it < 7) loadB(2 * it + 2, bE);          // prefetch even slice
        sliceA(2 * it + 1);
        mf(bO);
    }

    // ---- epilogue: direct stores. token = m0 + i*16 + lr; feats = f0 + j*16 + lg*4
    f32x4 bs4[4];
#pragma unroll
    for (int j = 0; j < 4; ++j)
        bs4[j] = *(const f32x4*)(bsum + f0 + j * 16 + lg * 4);

#pragma unroll
    for (int i = 0; i < 4; ++i) {
        const int row = m0 + i * 16 + lr;
        const float wt = wts[row];
#pragma unroll
        for (int j = 0; j < 4; ++j) {
            f32x4 v;
            v[0] = wt * (acc[j][i][0] + bs4[j][0]);
            v[1] = wt * (acc[j][i][1] + bs4[j][1]);
            v[2] = wt * (acc[j][i][2] + bs4[j][2]);
            v[3] = wt * (acc[j][i][3] + bs4[j][3]);
            *(f32x4*)(out + (size_t)row * DIM + f0 + j * 16 + lg * 4) = v;
        }
    }
}

extern "C" void kernel_launch(void* const* d_in, const int* in_sizes, int n_in,
                              void* d_out, int out_size, void* d_ws, size_t ws_size,
                              hipStream_t stream) {
    const float* x   = (const float*)d_in[0];   // [N, D]
    const float* wts = (const float*)d_in[1];   // [N, 1]
    const float* W   = (const float*)d_in[2];   // [E, D, D]
    const float* b   = (const float*)d_in[3];   // [E, D]
    float* out       = (float*)d_out;           // [N, D]

    unsigned short* Bfrag = (unsigned short*)d_ws;                    // 512 KB bf16
    float*          bsum  = (float*)((char*)d_ws + DIM * DIM * 2);    // 2 KB f32

    moe_prep<<<dim3((DIM * DIM / 8) / 256), dim3(256), 0, stream>>>(W, b, Bfrag, bsum);

    moe_gemm<<<dim3(N_TOK / BM), dim3(512), 0, stream>>>(x, wts, Bfrag, bsum, out);
}